// Round 8
// baseline (287.562 us; speedup 1.0000x reference)
//
#include <hip/hip_runtime.h>
#include <hip/hip_bf16.h>

// SelfAttention fused pipeline, bf16 MFMA path, K-split flash attention.
// x[4,512,48,48] -> GN(32) -> qkv 1x1 conv -> 8-head attn (N=2304,D=64) -> out proj.
//
// ws layout (66.66 MB):
//   po0  [4][2304][512] f32 @ 0          (first 9.44 MB doubles as xnT before attn)
//   po1  [4][2304][512] f32 @ 18874368
//   v    [4][512][2304] bf16 @ 37748736  (d-major; REUSED as innerT bf16 after attn)
//   qT   [4][8][2304][64] bf16 @ 47185920 (QSCALE folded via W_q staging)
//   kT   [4][8][2304][64] bf16 @ 56623104
//   pl   [2][4][8][2304] f32 @ 66060288
//   stats[4][32] float2     @ 66650112

typedef unsigned short u16;
typedef unsigned int u32;
typedef __attribute__((ext_vector_type(8))) short bf16x8;
typedef __attribute__((ext_vector_type(4))) float f32x4;
typedef __attribute__((ext_vector_type(8))) unsigned short us8;
typedef __attribute__((ext_vector_type(4))) unsigned short us4;

#define B_ 4
#define C_ 512
#define N_ 2304
#define H_ 8
#define D_ 64
#define G_ 32
#define SPLIT 2
#define KVB 96
#define PH (N_ / SPLIT / KVB)   // 12 phases per split block

// log2(e)/8: folded into W_q at staging so QK^T lands in exp2 domain.
#define QSCALE 0.1803368801111204f
// No max subtraction: exp2-domain scores |s| <~ 12, exp2(s) <= ~4096 fits
// f32/bf16 comfortably; softmax is shift-invariant.

__device__ __forceinline__ u16 f2bf(float f) {
  unsigned u = __float_as_uint(f);
  u += 0x7FFFu + ((u >> 16) & 1u);   // RNE
  return (u16)(u >> 16);
}

__device__ __forceinline__ u32 pack2bf(float lo, float hi) {
  __hip_bfloat162 t = __float22bfloat162_rn(float2{lo, hi});
  u32 r;
  __builtin_memcpy(&r, &t, 4);
  return r;
}

// ---------------- groupnorm stats: one block per (b,g) ----------------
__global__ __launch_bounds__(256) void gn_stats(const float* __restrict__ x,
                                                float2* __restrict__ stats) {
  const int bg = blockIdx.x;
  const float* p = x + (size_t)bg * 16 * N_;
  float s = 0.f, s2 = 0.f;
  for (int i = threadIdx.x; i < 16 * N_ / 4; i += 256) {
    const float4 v = ((const float4*)p)[i];
    s  += v.x + v.y + v.z + v.w;
    s2 += v.x * v.x + v.y * v.y + v.z * v.z + v.w * v.w;
  }
  #pragma unroll
  for (int off = 32; off; off >>= 1) { s += __shfl_down(s, off); s2 += __shfl_down(s2, off); }
  __shared__ float red[8];
  if ((threadIdx.x & 63) == 0) { red[(threadIdx.x >> 6) * 2] = s; red[(threadIdx.x >> 6) * 2 + 1] = s2; }
  __syncthreads();
  if (threadIdx.x == 0) {
    float S = 0.f, S2 = 0.f;
    for (int w = 0; w < 4; w++) { S += red[w * 2]; S2 += red[w * 2 + 1]; }
    const float inv = 1.f / (16.f * N_);
    const float mean = S * inv;
    const float var = S2 * inv - mean * mean;
    stats[bg] = make_float2(mean, rsqrtf(var + 1e-5f));
  }
}

// ---------------- GN apply + transpose -> xnT[b][n][c] bf16 ----------------
__global__ __launch_bounds__(256) void gn_apply_t(
    const float* __restrict__ x, const float2* __restrict__ stats,
    const float* __restrict__ gamma, const float* __restrict__ beta,
    u16* __restrict__ xnT) {
  __shared__ u16 T[64][72];
  const int c0 = blockIdx.x * 64, n0 = blockIdx.y * 64, b = blockIdx.z;
  const int r = threadIdx.x >> 2, ch = (threadIdx.x & 3) * 16;
  const int cc = c0 + r;
  const float2 st = stats[b * G_ + (cc >> 4)];
  const float sc = st.y * gamma[cc];
  const float sh = beta[cc] - st.x * sc;
  const float* src = x + (size_t)(b * C_ + cc) * N_ + n0 + ch;
  #pragma unroll
  for (int j = 0; j < 16; j += 4) {
    const float4 v = *(const float4*)(src + j);
    us4 o; o[0] = f2bf(v.x * sc + sh); o[1] = f2bf(v.y * sc + sh);
    o[2] = f2bf(v.z * sc + sh); o[3] = f2bf(v.w * sc + sh);
    *(us4*)&T[r][ch + j] = o;
  }
  __syncthreads();
  us8 o1, o2;
  #pragma unroll
  for (int j = 0; j < 8; j++) { o1[j] = T[ch + j][r]; o2[j] = T[ch + 8 + j][r]; }
  u16* dst = xnT + (size_t)(b * N_ + n0 + r) * C_ + c0 + ch;
  *(us8*)dst = o1;
  *(us8*)(dst + 8) = o2;
}

// ---------------- GEMM: C[bz][m][n] = A[m][k] * B[bz][n][k]^T ----------------
// A: f32 weights [M][K], cast to bf16 during LDS staging (MODE2 q-rows scaled).
// B: bf16 [bz][N][K] (K contiguous) for both modes.
// MODE 2 (qkv): epilogue scatters q->qT, k->kT (both [b][h][n][d]), v->vout (d-major).
// MODE 1 (out proj): f32 output + bias.
template <int MODE>
__global__ __launch_bounds__(256) void gemm_bf16(
    const float* __restrict__ Af, const u16* __restrict__ Bb16,
    void* __restrict__ C, const float* __restrict__ bias,
    u16* __restrict__ qT, u16* __restrict__ kT, u16* __restrict__ vout,
    const int M, const int N, const int K) {
  __shared__ u16 As[128][40];
  __shared__ u16 Bs[128][40];
  const int tid = threadIdx.x;
  const int wave = tid >> 6, lane = tid & 63;
  const int l16 = lane & 15, lq = lane >> 4;
  const int m0 = blockIdx.x * 128, n0 = blockIdx.y * 128, bz = blockIdx.z;
  const int wm = (wave >> 1) * 64, wn = (wave & 1) * 64;
  const u16* Bb = Bb16 + (size_t)bz * N * K;

  f32x4 acc[4][4];
  #pragma unroll
  for (int mi = 0; mi < 4; mi++)
    #pragma unroll
    for (int ni = 0; ni < 4; ni++) {
      acc[mi][ni][0] = 0.f; acc[mi][ni][1] = 0.f; acc[mi][ni][2] = 0.f; acc[mi][ni][3] = 0.f;
    }

  const int r = tid >> 2, c = (tid & 3) * 8;
  for (int kt = 0; kt < K; kt += 32) {
    __syncthreads();
    // A staging: f32 -> bf16 cast (+QSCALE fold for q rows in MODE2)
    #pragma unroll
    for (int half = 0; half < 2; half++) {
      const int row = m0 + r + half * 64;
      const float* ap = Af + (size_t)row * K + kt + c;
      const float4 f0 = *(const float4*)ap;
      const float4 f1 = *(const float4*)(ap + 4);
      const float sc = (MODE == 2 && row < 512) ? QSCALE : 1.0f;
      us8 o;
      o[0] = f2bf(f0.x * sc); o[1] = f2bf(f0.y * sc);
      o[2] = f2bf(f0.z * sc); o[3] = f2bf(f0.w * sc);
      o[4] = f2bf(f1.x * sc); o[5] = f2bf(f1.y * sc);
      o[6] = f2bf(f1.z * sc); o[7] = f2bf(f1.w * sc);
      *(us8*)&As[r + half * 64][c] = o;
    }
    *(us8*)&Bs[r][c]      = *(const us8*)&Bb[(size_t)(n0 + r) * K + kt + c];
    *(us8*)&Bs[r + 64][c] = *(const us8*)&Bb[(size_t)(n0 + r + 64) * K + kt + c];
    __syncthreads();
    bf16x8 af[4], bfr[4];
    #pragma unroll
    for (int mi = 0; mi < 4; mi++) af[mi] = *(const bf16x8*)&As[wm + mi * 16 + l16][lq * 8];
    #pragma unroll
    for (int ni = 0; ni < 4; ni++) bfr[ni] = *(const bf16x8*)&Bs[wn + ni * 16 + l16][lq * 8];
    #pragma unroll
    for (int mi = 0; mi < 4; mi++)
      #pragma unroll
      for (int ni = 0; ni < 4; ni++)
        acc[mi][ni] = __builtin_amdgcn_mfma_f32_16x16x32_bf16(af[mi], bfr[ni], acc[mi][ni], 0, 0, 0);
  }
  #pragma unroll
  for (int mi = 0; mi < 4; mi++) {
    const int row0 = m0 + wm + mi * 16 + lq * 4;
    #pragma unroll
    for (int ni = 0; ni < 4; ni++) {
      const int col = n0 + wn + ni * 16 + l16;
      if (MODE == 1) {
        #pragma unroll
        for (int j = 0; j < 4; j++) {
          const size_t idx = ((size_t)bz * M + row0 + j) * N + col;
          ((float*)C)[idx] = acc[mi][ni][j] + bias[row0 + j];
        }
      } else {
        const int which = row0 >> 9;           // 0=q, 1=k, 2=v
        if (which < 2) {
          const int h = (row0 >> 6) & 7, d0 = row0 & 63;
          u16* dst = which ? kT : qT;
          us4 o;
          #pragma unroll
          for (int j = 0; j < 4; j++) o[j] = f2bf(acc[mi][ni][j]);
          *(us4*)&dst[((size_t)((bz * H_ + h) * N_) + col) * D_ + d0] = o;
        } else {
          #pragma unroll
          for (int j = 0; j < 4; j++)
            vout[((size_t)(bz * 512) + (row0 & 511) + j) * N + col] = f2bf(acc[mi][ni][j]);
        }
      }
    }
  }
}

// ---------------- flash attention v8: KVB=96 phases (12 barriers), dist-1 prefetch ----------------
// block = (h, q-tile of 256, b*SPLIT+sp), 8 waves x 32 q-rows.
// Per phase: stage 96 k-rows of K + V (dbuf, distance-1 issued right after the
// barrier so the ~1.5x-longer compute phase covers HBM latency); compute as
// 3 groups of 32 k-rows: {QK (8 MFMA) -> exp2/pack -> PV (8 MFMA)}.
__global__ __launch_bounds__(512, 4) void attn_kernel8(
    const u16* __restrict__ qT, const u16* __restrict__ kT,
    const u16* __restrict__ vsec, float* __restrict__ po0,
    float* __restrict__ pl) {
  __shared__ u16 Ks[2][KVB][72];    // rows = k (96), cols = d (64) + pad (16B-aligned rows)
  __shared__ u16 Vs[2][D_][104];    // rows = d (64), cols = n (96, permuted) + pad

  const int h = blockIdx.x;
  const int b = blockIdx.z >> 1, sp = blockIdx.z & 1;
  const int q0 = blockIdx.y * 256;
  const int tid = threadIdx.x;
  const int wave = tid >> 6, lane = tid & 63;
  const int l16 = lane & 15, lq = lane >> 4;
  const int n0 = sp * (N_ / SPLIT);

  bf16x8 qf[2][2];
  {
    const u16* qb = qT + ((size_t)((b * H_ + h) * N_ + q0 + wave * 32)) * D_;
    #pragma unroll
    for (int qi = 0; qi < 2; qi++)
      #pragma unroll
      for (int dh = 0; dh < 2; dh++)
        qf[qi][dh] = *(const bf16x8*)(qb + (size_t)(qi * 16 + l16) * D_ + dh * 32 + lq * 8);
  }

  float l[2] = {0.f, 0.f};
  f32x4 acc[2][4];
  #pragma unroll
  for (int qi = 0; qi < 2; qi++)
    #pragma unroll
    for (int di = 0; di < 4; di++) {
      acc[qi][di][0] = 0.f; acc[qi][di][1] = 0.f; acc[qi][di][2] = 0.f; acc[qi][di][3] = 0.f;
    }
  const f32x4 z4 = {0.f, 0.f, 0.f, 0.f};

  const u16* kbase = kT + (size_t)(b * H_ + h) * N_ * D_;
  const u16* vbase = vsec + ((size_t)(b * 512) + h * D_) * N_;

  // staging chunk maps (768 us8 chunks per matrix per phase; tid and tid+512)
  const int kr0 = tid >> 3, kc = (tid & 7) * 8;
  const int kr1 = (tid + 512) >> 3;
  const int vr0 = tid / 12, vc0 = (tid % 12) * 8;
  const int vr1 = (tid + 512) / 12, vc1 = ((tid + 512) % 12) * 8;
  // permuted n-col within each 32-group: n=hi*16+lq2*4+j -> lq2*8+hi*4+j
  const int vcp0 = (vc0 & ~31) + (((vc0 >> 2) & 3) << 3) + (((vc0 >> 4) & 1) << 2);
  const int vcp1 = (vc1 & ~31) + (((vc1 >> 2) & 3) << 3) + (((vc1 >> 4) & 1) << 2);
  const bool lo = (tid < 256);   // wave-uniform

  // one phase's compute on LDS buffer `buf`
  auto PHASE = [&](const int buf) {
    #pragma unroll
    for (int g = 0; g < 3; g++) {
      f32x4 s[2][2];
      __builtin_amdgcn_s_setprio(1);
      #pragma unroll
      for (int nn = 0; nn < 2; nn++) {
        const int kr = g * 32 + nn * 16 + l16;
        const bf16x8 k0 = *(const bf16x8*)&Ks[buf][kr][lq * 8];
        const bf16x8 k1 = *(const bf16x8*)&Ks[buf][kr][32 + lq * 8];
        #pragma unroll
        for (int qi = 0; qi < 2; qi++) {
          s[qi][nn] = __builtin_amdgcn_mfma_f32_16x16x32_bf16(k0, qf[qi][0], z4, 0, 0, 0);
          s[qi][nn] = __builtin_amdgcn_mfma_f32_16x16x32_bf16(k1, qf[qi][1], s[qi][nn], 0, 0, 0);
        }
      }
      __builtin_amdgcn_s_setprio(0);

      union { u32 w[4]; bf16x8 v; } af[2];
      #pragma unroll
      for (int qi = 0; qi < 2; qi++) {
        float rs = 0.f;
        #pragma unroll
        for (int nn = 0; nn < 2; nn++) {
          const float p0 = __builtin_amdgcn_exp2f(s[qi][nn][0]);
          const float p1 = __builtin_amdgcn_exp2f(s[qi][nn][1]);
          const float p2 = __builtin_amdgcn_exp2f(s[qi][nn][2]);
          const float p3 = __builtin_amdgcn_exp2f(s[qi][nn][3]);
          rs += (p0 + p1) + (p2 + p3);
          af[qi].w[nn * 2]     = pack2bf(p0, p1);
          af[qi].w[nn * 2 + 1] = pack2bf(p2, p3);
        }
        l[qi] += rs;
      }

      __builtin_amdgcn_s_setprio(1);
      #pragma unroll
      for (int di = 0; di < 4; di++) {
        const bf16x8 vf = *(const bf16x8*)&Vs[buf][di * 16 + l16][g * 32 + lq * 8];
        #pragma unroll
        for (int qi = 0; qi < 2; qi++)
          acc[qi][di] = __builtin_amdgcn_mfma_f32_16x16x32_bf16(af[qi].v, vf, acc[qi][di], 0, 0, 0);
      }
      __builtin_amdgcn_s_setprio(0);
    }
  };

  // prologue: stage phase 0 into buffer 0
  {
    *(us8*)&Ks[0][kr0][kc] = *(const us8*)&kbase[(size_t)(n0 + kr0) * D_ + kc];
    us8 v0 = *(const us8*)&vbase[(size_t)vr0 * N_ + n0 + vc0];
    *(us4*)&Vs[0][vr0][vcp0]     = ((us4*)&v0)[0];
    *(us4*)&Vs[0][vr0][vcp0 + 8] = ((us4*)&v0)[1];
    if (lo) {
      *(us8*)&Ks[0][kr1][kc] = *(const us8*)&kbase[(size_t)(n0 + kr1) * D_ + kc];
      us8 v1 = *(const us8*)&vbase[(size_t)vr1 * N_ + n0 + vc1];
      *(us4*)&Vs[0][vr1][vcp1]     = ((us4*)&v1)[0];
      *(us4*)&Vs[0][vr1][vcp1 + 8] = ((us4*)&v1)[1];
    }
  }

  int cur = 0;
  for (int t = 0; t < PH; t++) {
    __syncthreads();
    const bool more = (t + 1 < PH);
    us8 pk0, pv0, pk1, pv1;
    if (more) {
      const int nn = n0 + (t + 1) * KVB;
      pk0 = *(const us8*)&kbase[(size_t)(nn + kr0) * D_ + kc];
      pv0 = *(const us8*)&vbase[(size_t)vr0 * N_ + nn + vc0];
      if (lo) {
        pk1 = *(const us8*)&kbase[(size_t)(nn + kr1) * D_ + kc];
        pv1 = *(const us8*)&vbase[(size_t)vr1 * N_ + nn + vc1];
      }
    }
    PHASE(cur);
    if (more) {
      *(us8*)&Ks[cur ^ 1][kr0][kc] = pk0;
      *(us4*)&Vs[cur ^ 1][vr0][vcp0]     = ((us4*)&pv0)[0];
      *(us4*)&Vs[cur ^ 1][vr0][vcp0 + 8] = ((us4*)&pv0)[1];
      if (lo) {
        *(us8*)&Ks[cur ^ 1][kr1][kc] = pk1;
        *(us4*)&Vs[cur ^ 1][vr1][vcp1]     = ((us4*)&pv1)[0];
        *(us4*)&Vs[cur ^ 1][vr1][vcp1 + 8] = ((us4*)&pv1)[1];
      }
    }
    cur ^= 1;
  }

  // ---- epilogue: write unnormalized partial O (f32) + partial l ----
  float* po = po0 + (size_t)sp * (B_ * N_ * 512);
  #pragma unroll
  for (int qi = 0; qi < 2; qi++) {
    l[qi] += __shfl_xor(l[qi], 16);
    l[qi] += __shfl_xor(l[qi], 32);
  }
  if (lq == 0) {
    #pragma unroll
    for (int qi = 0; qi < 2; qi++) {
      const int n = q0 + wave * 32 + qi * 16 + l16;
      pl[((size_t)((sp * B_ + b) * H_) + h) * N_ + n] = l[qi];
    }
  }
  #pragma unroll
  for (int qi = 0; qi < 2; qi++)
    #pragma unroll
    for (int di = 0; di < 4; di++)
      #pragma unroll
      for (int j = 0; j < 4; j++) {
        const int n = q0 + wave * 32 + qi * 16 + lq * 4 + j;
        po[((size_t)(b * N_) + n) * 512 + h * D_ + di * 16 + l16] = acc[qi][di][j];
      }
}

// ---------------- combine: innerT = (po0+po1) * 1/(pl0+pl1), bf16 ----------------
__global__ __launch_bounds__(256) void combine_norm(
    const float* __restrict__ po0, const float* __restrict__ po1,
    const float* __restrict__ pl, u16* __restrict__ innerT) {
  const int bn = blockIdx.x * 4 + (threadIdx.x >> 6);   // b*N + n
  const int b = bn / N_, n = bn - b * N_;
  const int c0 = (threadIdx.x & 63) * 8;
  const int h = c0 >> 6;
  const size_t lidx = ((size_t)(b * H_) + h) * N_ + n;
  const float rl = 1.0f / (pl[lidx] + pl[lidx + (size_t)B_ * H_ * N_]);
  const size_t base = (size_t)bn * 512 + c0;
  const float4 a0 = *(const float4*)&po0[base];
  const float4 a1 = *(const float4*)&po0[base + 4];
  const float4 b0 = *(const float4*)&po1[base];
  const float4 b1 = *(const float4*)&po1[base + 4];
  us8 o;
  o[0] = f2bf((a0.x + b0.x) * rl); o[1] = f2bf((a0.y + b0.y) * rl);
  o[2] = f2bf((a0.z + b0.z) * rl); o[3] = f2bf((a0.w + b0.w) * rl);
  o[4] = f2bf((a1.x + b1.x) * rl); o[5] = f2bf((a1.y + b1.y) * rl);
  o[6] = f2bf((a1.z + b1.z) * rl); o[7] = f2bf((a1.w + b1.w) * rl);
  *(us8*)&innerT[base] = o;
}

extern "C" void kernel_launch(void* const* d_in, const int* in_sizes, int n_in,
                              void* d_out, int out_size, void* d_ws, size_t ws_size,
                              hipStream_t stream) {
  const float* x     = (const float*)d_in[0];
  const float* gamma = (const float*)d_in[1];
  const float* beta  = (const float*)d_in[2];
  const float* w_qkv = (const float*)d_in[3];
  const float* w_out = (const float*)d_in[4];
  const float* b_out = (const float*)d_in[5];
  float* out = (float*)d_out;

  char* ws = (char*)d_ws;
  float*  po0    = (float*)(ws + 0);
  float*  po1    = (float*)(ws + 18874368);
  u16*    vsec   = (u16*)(ws + 37748736);
  u16*    qT     = (u16*)(ws + 47185920);
  u16*    kT     = (u16*)(ws + 56623104);
  float*  pl     = (float*)(ws + 66060288);
  float2* stats  = (float2*)(ws + 66650112);
  u16*    xnT    = (u16*)(ws + 0);          // aliases po0; dead after gemm1
  u16*    innerT = vsec;                    // aliases vsec; vsec dead after attn

  gn_stats<<<dim3(B_ * G_), dim3(256), 0, stream>>>(x, stats);
  gn_apply_t<<<dim3(C_ / 64, N_ / 64, B_), dim3(256), 0, stream>>>(x, stats, gamma, beta, xnT);
  gemm_bf16<2><<<dim3(12, 18, B_), dim3(256), 0, stream>>>(
      w_qkv, xnT, nullptr, nullptr, qT, kT, vsec, 1536, N_, C_);
  attn_kernel8<<<dim3(H_, N_ / 256, B_ * SPLIT), dim3(512), 0, stream>>>(qT, kT, vsec, po0, pl);
  combine_norm<<<dim3(B_ * N_ / 4), dim3(256), 0, stream>>>(po0, po1, pl, innerT);
  gemm_bf16<1><<<dim3(4, 18, B_), dim3(256), 0, stream>>>(
      w_out, innerT, (void*)out, b_out, nullptr, nullptr, nullptr, C_, N_, C_);
}

// Round 9
// 155.369 us; speedup vs baseline: 1.8508x; 1.8508x over previous
//
#include <hip/hip_runtime.h>
#include <hip/hip_bf16.h>

// SelfAttention fused pipeline, bf16 MFMA path, K-split flash attention.
// x[4,512,48,48] -> GN(32) -> qkv 1x1 conv -> 8-head attn (N=2304,D=64) -> out proj.
//
// ws layout (66.66 MB):
//   po0  [4][2304][512] f32 @ 0          (first 9.44 MB doubles as xnT before attn)
//   po1  [4][2304][512] f32 @ 18874368
//   v    [4][512][2304] bf16 @ 37748736  (d-major, n-permuted per 32-group; innerT after attn)
//   qT   [4][8][2304][64] bf16 @ 47185920 (QSCALE folded via W_q staging)
//   kT   [4][8][2304][64] bf16 @ 56623104
//   pl   [2][4][8][2304] f32 @ 66060288
//   stats[4][32] float2     @ 66650112

typedef unsigned short u16;
typedef unsigned int u32;
typedef __attribute__((ext_vector_type(8))) short bf16x8;
typedef __attribute__((ext_vector_type(4))) float f32x4;
typedef __attribute__((ext_vector_type(8))) unsigned short us8;
typedef __attribute__((ext_vector_type(4))) unsigned short us4;

#define B_ 4
#define C_ 512
#define N_ 2304
#define H_ 8
#define D_ 64
#define G_ 32
#define SPLIT 2
#define NT (N_ / 64 / SPLIT)   // 18 k-tiles per split block

// log2(e)/8: folded into W_q at staging so QK^T lands in exp2 domain.
#define QSCALE 0.1803368801111204f
// No max subtraction: exp2-domain scores |s| <~ 12, exp2(s) <= ~4096 fits
// f32/bf16 comfortably; softmax is shift-invariant.

__device__ __forceinline__ u16 f2bf(float f) {
  unsigned u = __float_as_uint(f);
  u += 0x7FFFu + ((u >> 16) & 1u);   // RNE
  return (u16)(u >> 16);
}

__device__ __forceinline__ u32 pack2bf(float lo, float hi) {
  __hip_bfloat162 t = __float22bfloat162_rn(float2{lo, hi});
  u32 r;
  __builtin_memcpy(&r, &t, 4);
  return r;
}

// ---------------- groupnorm stats: one block per (b,g) ----------------
__global__ __launch_bounds__(256) void gn_stats(const float* __restrict__ x,
                                                float2* __restrict__ stats) {
  const int bg = blockIdx.x;
  const float* p = x + (size_t)bg * 16 * N_;
  float s = 0.f, s2 = 0.f;
  for (int i = threadIdx.x; i < 16 * N_ / 4; i += 256) {
    const float4 v = ((const float4*)p)[i];
    s  += v.x + v.y + v.z + v.w;
    s2 += v.x * v.x + v.y * v.y + v.z * v.z + v.w * v.w;
  }
  #pragma unroll
  for (int off = 32; off; off >>= 1) { s += __shfl_down(s, off); s2 += __shfl_down(s2, off); }
  __shared__ float red[8];
  if ((threadIdx.x & 63) == 0) { red[(threadIdx.x >> 6) * 2] = s; red[(threadIdx.x >> 6) * 2 + 1] = s2; }
  __syncthreads();
  if (threadIdx.x == 0) {
    float S = 0.f, S2 = 0.f;
    for (int w = 0; w < 4; w++) { S += red[w * 2]; S2 += red[w * 2 + 1]; }
    const float inv = 1.f / (16.f * N_);
    const float mean = S * inv;
    const float var = S2 * inv - mean * mean;
    stats[bg] = make_float2(mean, rsqrtf(var + 1e-5f));
  }
}

// ---------------- GN apply + transpose -> xnT[b][n][c] bf16 ----------------
__global__ __launch_bounds__(256) void gn_apply_t(
    const float* __restrict__ x, const float2* __restrict__ stats,
    const float* __restrict__ gamma, const float* __restrict__ beta,
    u16* __restrict__ xnT) {
  __shared__ u16 T[64][72];
  const int c0 = blockIdx.x * 64, n0 = blockIdx.y * 64, b = blockIdx.z;
  const int r = threadIdx.x >> 2, ch = (threadIdx.x & 3) * 16;
  const int cc = c0 + r;
  const float2 st = stats[b * G_ + (cc >> 4)];
  const float sc = st.y * gamma[cc];
  const float sh = beta[cc] - st.x * sc;
  const float* src = x + (size_t)(b * C_ + cc) * N_ + n0 + ch;
  #pragma unroll
  for (int j = 0; j < 16; j += 4) {
    const float4 v = *(const float4*)(src + j);
    us4 o; o[0] = f2bf(v.x * sc + sh); o[1] = f2bf(v.y * sc + sh);
    o[2] = f2bf(v.z * sc + sh); o[3] = f2bf(v.w * sc + sh);
    *(us4*)&T[r][ch + j] = o;
  }
  __syncthreads();
  us8 o1, o2;
  #pragma unroll
  for (int j = 0; j < 8; j++) { o1[j] = T[ch + j][r]; o2[j] = T[ch + 8 + j][r]; }
  u16* dst = xnT + (size_t)(b * N_ + n0 + r) * C_ + c0 + ch;
  *(us8*)dst = o1;
  *(us8*)(dst + 8) = o2;
}

// ---------------- GEMM: C[bz][m][n] = A[m][k] * B[bz][n][k]^T ----------------
// A: f32 weights [M][K], cast to bf16 during LDS staging (MODE2 q-rows scaled).
// B: bf16 [bz][N][K] (K contiguous) for both modes.
// MODE 2 (qkv): epilogue scatters q->qT, k->kT (both [b][h][n][d]), v->vout (d-major).
// MODE 1 (out proj): f32 output + bias.
template <int MODE>
__global__ __launch_bounds__(256) void gemm_bf16(
    const float* __restrict__ Af, const u16* __restrict__ Bb16,
    void* __restrict__ C, const float* __restrict__ bias,
    u16* __restrict__ qT, u16* __restrict__ kT, u16* __restrict__ vout,
    const int M, const int N, const int K) {
  __shared__ u16 As[128][40];
  __shared__ u16 Bs[128][40];
  const int tid = threadIdx.x;
  const int wave = tid >> 6, lane = tid & 63;
  const int l16 = lane & 15, lq = lane >> 4;
  const int m0 = blockIdx.x * 128, n0 = blockIdx.y * 128, bz = blockIdx.z;
  const int wm = (wave >> 1) * 64, wn = (wave & 1) * 64;
  const u16* Bb = Bb16 + (size_t)bz * N * K;

  f32x4 acc[4][4];
  #pragma unroll
  for (int mi = 0; mi < 4; mi++)
    #pragma unroll
    for (int ni = 0; ni < 4; ni++) {
      acc[mi][ni][0] = 0.f; acc[mi][ni][1] = 0.f; acc[mi][ni][2] = 0.f; acc[mi][ni][3] = 0.f;
    }

  const int r = tid >> 2, c = (tid & 3) * 8;
  for (int kt = 0; kt < K; kt += 32) {
    __syncthreads();
    // A staging: f32 -> bf16 cast (+QSCALE fold for q rows in MODE2)
    #pragma unroll
    for (int half = 0; half < 2; half++) {
      const int row = m0 + r + half * 64;
      const float* ap = Af + (size_t)row * K + kt + c;
      const float4 f0 = *(const float4*)ap;
      const float4 f1 = *(const float4*)(ap + 4);
      const float sc = (MODE == 2 && row < 512) ? QSCALE : 1.0f;
      us8 o;
      o[0] = f2bf(f0.x * sc); o[1] = f2bf(f0.y * sc);
      o[2] = f2bf(f0.z * sc); o[3] = f2bf(f0.w * sc);
      o[4] = f2bf(f1.x * sc); o[5] = f2bf(f1.y * sc);
      o[6] = f2bf(f1.z * sc); o[7] = f2bf(f1.w * sc);
      *(us8*)&As[r + half * 64][c] = o;
    }
    *(us8*)&Bs[r][c]      = *(const us8*)&Bb[(size_t)(n0 + r) * K + kt + c];
    *(us8*)&Bs[r + 64][c] = *(const us8*)&Bb[(size_t)(n0 + r + 64) * K + kt + c];
    __syncthreads();
    bf16x8 af[4], bfr[4];
    #pragma unroll
    for (int mi = 0; mi < 4; mi++) af[mi] = *(const bf16x8*)&As[wm + mi * 16 + l16][lq * 8];
    #pragma unroll
    for (int ni = 0; ni < 4; ni++) bfr[ni] = *(const bf16x8*)&Bs[wn + ni * 16 + l16][lq * 8];
    #pragma unroll
    for (int mi = 0; mi < 4; mi++)
      #pragma unroll
      for (int ni = 0; ni < 4; ni++)
        acc[mi][ni] = __builtin_amdgcn_mfma_f32_16x16x32_bf16(af[mi], bfr[ni], acc[mi][ni], 0, 0, 0);
  }
  #pragma unroll
  for (int mi = 0; mi < 4; mi++) {
    const int row0 = m0 + wm + mi * 16 + lq * 4;
    #pragma unroll
    for (int ni = 0; ni < 4; ni++) {
      const int col = n0 + wn + ni * 16 + l16;
      if (MODE == 1) {
        #pragma unroll
        for (int j = 0; j < 4; j++) {
          const size_t idx = ((size_t)bz * M + row0 + j) * N + col;
          ((float*)C)[idx] = acc[mi][ni][j] + bias[row0 + j];
        }
      } else {
        const int which = row0 >> 9;           // 0=q, 1=k, 2=v
        if (which < 2) {
          const int h = (row0 >> 6) & 7, d0 = row0 & 63;
          u16* dst = which ? kT : qT;
          us4 o;
          #pragma unroll
          for (int j = 0; j < 4; j++) o[j] = f2bf(acc[mi][ni][j]);
          *(us4*)&dst[((size_t)((bz * H_ + h) * N_) + col) * D_ + d0] = o;
        } else {
          #pragma unroll
          for (int j = 0; j < 4; j++)
            vout[((size_t)(bz * 512) + (row0 & 511) + j) * N + col] = f2bf(acc[mi][ni][j]);
        }
      }
    }
  }
}

// ---------------- flash attention v9: v5 structure, 16 q-rows/wave ----------------
// block = (h, q-tile of 128, b*SPLIT+sp), 8 waves x 16 q-rows, 18 k-tiles.
// Grid 1152 blocks; LDS 36.9KB -> 4 blocks/CU co-resident -> up to 32 waves/CU.
// S^T = mfma(A=K, B=Q), no max subtraction, l in-lane, P packed in-register,
// V staged n-permuted in LDS so PV b-frag is one b128 read.
__global__ __launch_bounds__(512) void attn_kernel9(
    const u16* __restrict__ qT, const u16* __restrict__ kT,
    const u16* __restrict__ vsec, float* __restrict__ po0,
    float* __restrict__ pl) {
  __shared__ u16 Ks[2][64][72];
  __shared__ u16 Vs[2][64][72];

  const int h = blockIdx.x;
  const int b = blockIdx.z >> 1, sp = blockIdx.z & 1;
  const int q0 = blockIdx.y * 128;
  const int tid = threadIdx.x;
  const int wave = tid >> 6, lane = tid & 63;
  const int l16 = lane & 15, lq = lane >> 4;
  const int kt0 = sp * NT;

  // Q fragments (B-operand: lane row = q_local = l16), 16 rows per wave
  bf16x8 qf[2];
  {
    const u16* qb = qT + ((size_t)((b * H_ + h) * N_ + q0 + wave * 16 + l16)) * D_;
    qf[0] = *(const bf16x8*)(qb + lq * 8);
    qf[1] = *(const bf16x8*)(qb + 32 + lq * 8);
  }

  float l = 0.f;
  f32x4 acc[4];
  #pragma unroll
  for (int di = 0; di < 4; di++) {
    acc[di][0] = 0.f; acc[di][1] = 0.f; acc[di][2] = 0.f; acc[di][3] = 0.f;
  }
  const f32x4 z4 = {0.f, 0.f, 0.f, 0.f};   // shared C-input for first QK MFMA

  const u16* kbase = kT + (size_t)(b * H_ + h) * N_ * D_;
  const u16* vbase = vsec + ((size_t)(b * 512) + h * D_) * N_;
  // 512 threads stage 64x64 K + 64x64 V: one us8 of each per thread.
  const int sr = tid >> 3, sc = (tid & 7) * 8;
  // permuted V columns so PV b-frag is one b128 read (perm within 32-group)
  const int cb = sc & 31;
  const int colp = (sc & ~31) + ((cb >> 2) & 3) * 8 + ((cb >> 4) & 1) * 4;

  // prologue: stage tile kt0
  {
    *(us8*)&Ks[0][sr][sc] = *(const us8*)&kbase[(size_t)(kt0 * 64 + sr) * D_ + sc];
    us8 v0 = *(const us8*)&vbase[(size_t)sr * N_ + kt0 * 64 + sc];
    *(us4*)&Vs[0][sr][colp]     = ((us4*)&v0)[0];
    *(us4*)&Vs[0][sr][colp + 8] = ((us4*)&v0)[1];
  }

  int cur = 0;
  for (int t = 0; t < NT; t++) {
    const int kt = kt0 + t;
    __syncthreads();

    us8 nk0, nv0;
    const bool more = (t + 1 < NT);
    if (more) {
      nk0 = *(const us8*)&kbase[(size_t)((kt + 1) * 64 + sr) * D_ + sc];
      nv0 = *(const us8*)&vbase[(size_t)sr * N_ + (kt + 1) * 64 + sc];
    }

    // ---- S^T = K Q^T ----
    f32x4 s[4];
    __builtin_amdgcn_s_setprio(1);
    #pragma unroll
    for (int ni = 0; ni < 4; ni++) {
      const bf16x8 k0 = *(const bf16x8*)&Ks[cur][ni * 16 + l16][lq * 8];
      const bf16x8 k1 = *(const bf16x8*)&Ks[cur][ni * 16 + l16][32 + lq * 8];
      s[ni] = __builtin_amdgcn_mfma_f32_16x16x32_bf16(k0, qf[0], z4, 0, 0, 0);
      s[ni] = __builtin_amdgcn_mfma_f32_16x16x32_bf16(k1, qf[1], s[ni], 0, 0, 0);
    }
    __builtin_amdgcn_s_setprio(0);

    // ---- p = exp2(s); l in-lane; pack directly into PV a-frag words ----
    union { u32 w[4]; bf16x8 v; } af[2];   // [kh]
    float rs = 0.f;
    #pragma unroll
    for (int ni = 0; ni < 4; ni++) {
      const float p0 = __builtin_amdgcn_exp2f(s[ni][0]);
      const float p1 = __builtin_amdgcn_exp2f(s[ni][1]);
      const float p2 = __builtin_amdgcn_exp2f(s[ni][2]);
      const float p3 = __builtin_amdgcn_exp2f(s[ni][3]);
      rs += (p0 + p1) + (p2 + p3);
      af[ni >> 1].w[(ni & 1) * 2]     = pack2bf(p0, p1);
      af[ni >> 1].w[(ni & 1) * 2 + 1] = pack2bf(p2, p3);
    }
    l += rs;

    // ---- PV: V b-frags one b128 each (n-permutation pre-applied at staging) ----
    __builtin_amdgcn_s_setprio(1);
    #pragma unroll
    for (int kh = 0; kh < 2; kh++)
      #pragma unroll
      for (int di = 0; di < 4; di++) {
        const bf16x8 vf = *(const bf16x8*)&Vs[cur][di * 16 + l16][kh * 32 + lq * 8];
        acc[di] = __builtin_amdgcn_mfma_f32_16x16x32_bf16(af[kh].v, vf, acc[di], 0, 0, 0);
      }
    __builtin_amdgcn_s_setprio(0);

    // late LDS write of the prefetched tile
    if (more) {
      *(us8*)&Ks[cur ^ 1][sr][sc] = nk0;
      *(us4*)&Vs[cur ^ 1][sr][colp]     = ((us4*)&nv0)[0];
      *(us4*)&Vs[cur ^ 1][sr][colp + 8] = ((us4*)&nv0)[1];
    }
    cur ^= 1;
  }

  // ---- epilogue: write unnormalized partial O (f32) + partial l ----
  float* po = po0 + (size_t)sp * (B_ * N_ * 512);
  l += __shfl_xor(l, 16);
  l += __shfl_xor(l, 32);
  if (lq == 0) {
    const int n = q0 + wave * 16 + l16;
    pl[((size_t)((sp * B_ + b) * H_) + h) * N_ + n] = l;
  }
  #pragma unroll
  for (int di = 0; di < 4; di++)
    #pragma unroll
    for (int j = 0; j < 4; j++) {
      const int n = q0 + wave * 16 + lq * 4 + j;
      po[((size_t)(b * N_) + n) * 512 + h * D_ + di * 16 + l16] = acc[di][j];
    }
}

// ---------------- combine: innerT = (po0+po1) * 1/(pl0+pl1), bf16 ----------------
__global__ __launch_bounds__(256) void combine_norm(
    const float* __restrict__ po0, const float* __restrict__ po1,
    const float* __restrict__ pl, u16* __restrict__ innerT) {
  const int bn = blockIdx.x * 4 + (threadIdx.x >> 6);   // b*N + n
  const int b = bn / N_, n = bn - b * N_;
  const int c0 = (threadIdx.x & 63) * 8;
  const int h = c0 >> 6;
  const size_t lidx = ((size_t)(b * H_) + h) * N_ + n;
  const float rl = 1.0f / (pl[lidx] + pl[lidx + (size_t)B_ * H_ * N_]);
  const size_t base = (size_t)bn * 512 + c0;
  const float4 a0 = *(const float4*)&po0[base];
  const float4 a1 = *(const float4*)&po0[base + 4];
  const float4 b0 = *(const float4*)&po1[base];
  const float4 b1 = *(const float4*)&po1[base + 4];
  us8 o;
  o[0] = f2bf((a0.x + b0.x) * rl); o[1] = f2bf((a0.y + b0.y) * rl);
  o[2] = f2bf((a0.z + b0.z) * rl); o[3] = f2bf((a0.w + b0.w) * rl);
  o[4] = f2bf((a1.x + b1.x) * rl); o[5] = f2bf((a1.y + b1.y) * rl);
  o[6] = f2bf((a1.z + b1.z) * rl); o[7] = f2bf((a1.w + b1.w) * rl);
  *(us8*)&innerT[base] = o;
}

extern "C" void kernel_launch(void* const* d_in, const int* in_sizes, int n_in,
                              void* d_out, int out_size, void* d_ws, size_t ws_size,
                              hipStream_t stream) {
  const float* x     = (const float*)d_in[0];
  const float* gamma = (const float*)d_in[1];
  const float* beta  = (const float*)d_in[2];
  const float* w_qkv = (const float*)d_in[3];
  const float* w_out = (const float*)d_in[4];
  const float* b_out = (const float*)d_in[5];
  float* out = (float*)d_out;

  char* ws = (char*)d_ws;
  float*  po0    = (float*)(ws + 0);
  float*  po1    = (float*)(ws + 18874368);
  u16*    vsec   = (u16*)(ws + 37748736);
  u16*    qT     = (u16*)(ws + 47185920);
  u16*    kT     = (u16*)(ws + 56623104);
  float*  pl     = (float*)(ws + 66060288);
  float2* stats  = (float2*)(ws + 66650112);
  u16*    xnT    = (u16*)(ws + 0);          // aliases po0; dead after gemm1
  u16*    innerT = vsec;                    // aliases vsec; vsec dead after attn

  gn_stats<<<dim3(B_ * G_), dim3(256), 0, stream>>>(x, stats);
  gn_apply_t<<<dim3(C_ / 64, N_ / 64, B_), dim3(256), 0, stream>>>(x, stats, gamma, beta, xnT);
  gemm_bf16<2><<<dim3(12, 18, B_), dim3(256), 0, stream>>>(
      w_qkv, xnT, nullptr, nullptr, qT, kT, vsec, 1536, N_, C_);
  attn_kernel9<<<dim3(H_, N_ / 128, B_ * SPLIT), dim3(512), 0, stream>>>(qT, kT, vsec, po0, pl);
  combine_norm<<<dim3(B_ * N_ / 4), dim3(256), 0, stream>>>(po0, po1, pl, innerT);
  gemm_bf16<1><<<dim3(4, 18, B_), dim3(256), 0, stream>>>(
      w_out, innerT, (void*)out, b_out, nullptr, nullptr, nullptr, C_, N_, C_);
}